// Round 4
// baseline (119.723 us; speedup 1.0000x reference)
//
#include <hip/hip_runtime.h>
#include <hip/hip_bf16.h>
#include <stdint.h>

#define DD 256
#define NB 16
#define NN 1024
#define MTOT (NB * NN)  // 16384

typedef __attribute__((ext_vector_type(8))) short short8;
typedef __attribute__((ext_vector_type(4))) float f32x4;

__device__ __forceinline__ ushort f2b(float f) {
  uint32_t u = __float_as_uint(f);
  return (ushort)((u + 0x7fffu + ((u >> 16) & 1u)) >> 16);
}

// ---------------------------------------------------------------------------
// graph [16,1024,1024] int32 -> bitmask [16,1024,32] uint32
__global__ __launch_bounds__(256) void pack_mask(const int* __restrict__ graph,
                                                 uint* __restrict__ maskG) {
  const int lane = threadIdx.x & 63;
  const int wid = (blockIdx.x * blockDim.x + threadIdx.x) >> 6;
  const int nwaves = (gridDim.x * blockDim.x) >> 6;
  for (long base = (long)wid * 64; base < 16L * 1024 * 1024;
       base += (long)nwaves * 64) {
    int g = graph[base + lane];
    unsigned long long m = __ballot(g != 0);
    if (lane == 0) {
      *(uint2*)(maskG + (base >> 5)) = make_uint2((uint)m, (uint)(m >> 32));
    }
  }
}

// ---------------------------------------------------------------------------
// C[m][e] = sum_k A[m][k] * W[e][k] + bias[e];  M=16384, K=E=256
template <bool A_F32, bool WRITE_T>
__global__ __launch_bounds__(256, 1) void gemm_hqk(
    const void* __restrict__ Aptr, const float* __restrict__ W,
    const float* __restrict__ bias, ushort* __restrict__ C,
    ushort* __restrict__ CT) {
  __shared__ ushort Wl[256 * 256];  // 128 KB, bf16, XOR-swizzled
  const int tid = threadIdx.x;

  for (int i = 0; i < 64; ++i) {
    int idx4 = i * 256 + tid;
    int row = idx4 >> 6;
    int col0 = (idx4 & 63) << 2;
    float4 v = ((const float4*)W)[idx4];
    ushort4 b4;
    b4.x = f2b(v.x); b4.y = f2b(v.y); b4.z = f2b(v.z); b4.w = f2b(v.w);
    int byte = (row * 512 + col0 * 2) ^ ((row & 7) << 4);
    *(ushort4*)((char*)Wl + byte) = b4;
  }
  __syncthreads();

  const int w = tid >> 6, lane = tid & 63, l15 = lane & 15, hi = lane >> 4;
  const int m0 = blockIdx.x * 64 + w * 16;
  const int arow = m0 + l15;

  f32x4 acc[16] = {};

#pragma unroll
  for (int kk = 0; kk < 8; ++kk) {
    const int k0 = kk * 32 + hi * 8;
    short8 a;
    if constexpr (A_F32) {
      const float4* ap = (const float4*)((const float*)Aptr + arow * 256 + k0);
      float4 x = ap[0], y = ap[1];
      a[0] = (short)f2b(x.x); a[1] = (short)f2b(x.y);
      a[2] = (short)f2b(x.z); a[3] = (short)f2b(x.w);
      a[4] = (short)f2b(y.x); a[5] = (short)f2b(y.y);
      a[6] = (short)f2b(y.z); a[7] = (short)f2b(y.w);
    } else {
      a = *(const short8*)((const ushort*)Aptr + arow * 256 + k0);
    }
#pragma unroll
    for (int et = 0; et < 16; ++et) {
      int er = et * 16 + l15;
      short8 bf = *(const short8*)((const char*)Wl +
                                   ((er * 512 + k0 * 2) ^ ((er & 7) << 4)));
      acc[et] = __builtin_amdgcn_mfma_f32_16x16x32_bf16(a, bf, acc[et], 0, 0, 0);
    }
  }

  ushort hvals[16][4];
#pragma unroll
  for (int et = 0; et < 16; ++et) {
    int e = et * 16 + l15;
    float bv = bias[e];
#pragma unroll
    for (int r = 0; r < 4; ++r) {
      ushort hb = f2b(acc[et][r] + bv);
      hvals[et][r] = hb;
      C[(m0 + hi * 4 + r) * 256 + e] = hb;
    }
  }

  if constexpr (WRITE_T) {
    __syncthreads();  // done reading Wl; reuse as transpose buffer [256][64]
    ushort* Tl = Wl;
    const int mloc = w * 16 + hi * 4;
#pragma unroll
    for (int et = 0; et < 16; ++et)
#pragma unroll
      for (int r = 0; r < 4; ++r)
        Tl[(et * 16 + l15) * 64 + mloc + r] = hvals[et][r];
    __syncthreads();
    const int bidx = blockIdx.x >> 4;
    const int n0 = (blockIdx.x & 15) * 64;
    ushort* dst = CT + bidx * (256 * 1024) + tid * 1024 + n0;
    const uint4* src = (const uint4*)(Tl + tid * 64);
#pragma unroll
    for (int j = 0; j < 8; ++j) ((uint4*)dst)[j] = src[j];
  }
}

// ---------------------------------------------------------------------------
// Fused attention, 8 waves: wave-pair splits the 64-key tile (half*32 keys).
// Shared memory is one explicit arena (layout is load-bearing: the epilogue
// reuses [0, 64K) as the fp32 pair-combine buffer).
#define SM_KT 0        // ushort Kt[64*256]   32768 B
#define SM_HT 32768    // ushort Ht[256*64]   32768 B
#define SM_PL 65536    // ushort Pl[8*16*32]   8192 B
#define SM_MK 73728    // uint   Mask[64*33]   8448 B
#define SM_CM 82176    // float  Cm[64*2]       512 B
#define SM_SZ 82688

__global__ __launch_bounds__(512, 2) void attn8(
    const ushort* __restrict__ Q, const ushort* __restrict__ Kb,
    const ushort* __restrict__ HT, const uint* __restrict__ maskG,
    float* __restrict__ out) {
  __shared__ __align__(16) char smem[SM_SZ];
  ushort* Kt = (ushort*)(smem + SM_KT);
  ushort* Ht = (ushort*)(smem + SM_HT);
  ushort* Pl = (ushort*)(smem + SM_PL);
  uint* Mask = (uint*)(smem + SM_MK);
  float* Cm = (float*)(smem + SM_CM);

  const int tid = threadIdx.x;
  const int w = tid >> 6, lane = tid & 63, l15 = lane & 15, hi = lane >> 4;
  const int wg = w >> 1, half = w & 1;
  // XCD-aware remap: XCD x handles batches {2x, 2x+1}
  const int hw = blockIdx.x;
  const int slot = hw >> 3;
  const int b = (hw & 7) * 2 + (slot >> 4);
  const int q0 = (slot & 15) * 64;
  const int qrow_a = q0 + wg * 16 + l15;
  const int qrow_cl = wg * 16 + hi * 4;  // local row base (+r)

  // stage this block's mask rows (64 x 32 words)
  {
    const uint* src = maskG + (b * 1024 + q0) * 32;
#pragma unroll
    for (int i = 0; i < 4; ++i) {
      int idx = i * 512 + tid;
      Mask[(idx >> 5) * 33 + (idx & 31)] = src[idx];
    }
  }

  // hoist Q fragments
  short8 qf[8];
#pragma unroll
  for (int kk = 0; kk < 8; ++kk)
    qf[kk] = *(const short8*)(Q + (b * 1024 + qrow_a) * 256 + kk * 32 + hi * 8);

  float mR[4] = {-1e30f, -1e30f, -1e30f, -1e30f};
  float lR[4] = {0.f, 0.f, 0.f, 0.f};
  float corr[4];
  f32x4 o[16] = {};

  for (int t = 0; t < 16; ++t) {
    __syncthreads();
#pragma unroll
    for (int i = 0; i < 4; ++i) {  // stage K tile [64][256]
      int c = i * 512 + tid;
      int krow = c >> 5, col0 = (c & 31) << 3;
      uint4 v = *(const uint4*)(Kb + (b * 1024 + t * 64 + krow) * 256 + col0);
      *(uint4*)((char*)Kt + ((krow * 512 + col0 * 2) ^ ((krow & 7) << 4))) = v;
    }
#pragma unroll
    for (int i = 0; i < 4; ++i) {  // stage H^T tile [256][64]
      int c = i * 512 + tid;
      int drow = c >> 3, col0 = (c & 7) << 3;
      uint4 v = *(const uint4*)(HT + b * (256 * 1024) + drow * 1024 + t * 64 + col0);
      *(uint4*)((char*)Ht + ((drow * 128 + col0 * 2) ^ ((drow & 7) << 4))) = v;
    }
    __syncthreads();

    // S = q @ k^T : 16 rows x 32 keys (this wave's half)
    f32x4 s[2] = {};
#pragma unroll
    for (int kk = 0; kk < 8; ++kk) {
#pragma unroll
      for (int nt = 0; nt < 2; ++nt) {
        int krow = half * 32 + nt * 16 + l15;
        short8 kf = *(const short8*)((const char*)Kt +
            ((krow * 512 + (kk * 32 + hi * 8) * 2) ^ ((krow & 7) << 4)));
        s[nt] = __builtin_amdgcn_mfma_f32_16x16x32_bf16(qf[kk], kf, s[nt], 0, 0, 0);
      }
    }

    // scale, leaky, mask (from LDS bitmask), online softmax w/ defer-max
    float p[2][4];
    bool anyGrow = false;
#pragma unroll
    for (int r = 0; r < 4; ++r) {
      uint mw = Mask[(qrow_cl + r) * 33 + t * 2 + half];
      float v0 = s[0][r] * 0.0625f; v0 = (v0 >= 0.f) ? v0 : 0.2f * v0;
      float v1 = s[1][r] * 0.0625f; v1 = (v1 >= 0.f) ? v1 : 0.2f * v1;
      v0 = ((mw >> l15) & 1u) ? v0 : -1e9f;
      v1 = ((mw >> (16 + l15)) & 1u) ? v1 : -1e9f;
      float rm = fmaxf(v0, v1);
      rm = fmaxf(rm, __shfl_xor(rm, 1));
      rm = fmaxf(rm, __shfl_xor(rm, 2));
      rm = fmaxf(rm, __shfl_xor(rm, 4));
      rm = fmaxf(rm, __shfl_xor(rm, 8));
      bool grow = rm > mR[r] + 8.f;
      float mn = grow ? rm : mR[r];
      corr[r] = grow ? __expf(mR[r] - mn) : 1.f;
      mR[r] = mn;
      anyGrow |= grow;
      float p0 = __expf(v0 - mn), p1 = __expf(v1 - mn);
      p[0][r] = p0; p[1][r] = p1;
      float rs = p0 + p1;
      rs += __shfl_xor(rs, 1);
      rs += __shfl_xor(rs, 2);
      rs += __shfl_xor(rs, 4);
      rs += __shfl_xor(rs, 8);
      lR[r] = lR[r] * corr[r] + rs;
    }
    if (__any(anyGrow)) {
#pragma unroll
      for (int dt = 0; dt < 16; ++dt)
#pragma unroll
        for (int r = 0; r < 4; ++r) o[dt][r] *= corr[r];
    }

    // P (C-layout) -> per-wave LDS -> A-frag layout
    ushort* Pw = Pl + w * 512;
#pragma unroll
    for (int nt = 0; nt < 2; ++nt)
#pragma unroll
      for (int r = 0; r < 4; ++r) {
        int row = hi * 4 + r, col = nt * 16 + l15;
        *(ushort*)((char*)Pw +
                   ((row * 64 + col * 2) ^ (((row >> 2) & 3) << 4))) =
            f2b(p[nt][r]);
      }
    __asm__ volatile("s_waitcnt lgkmcnt(0)" ::: "memory");
    short8 pa = *(const short8*)((const char*)Pw +
        ((l15 * 64 + hi * 16) ^ (((l15 >> 2) & 3) << 4)));

    // O += P @ H (keys half*32 .. half*32+31)
#pragma unroll
    for (int dt = 0; dt < 16; ++dt) {
      int dcol = dt * 16 + l15;
      short8 hf = *(const short8*)((const char*)Ht +
          ((dcol * 128 + (half * 32 + hi * 8) * 2) ^ ((dcol & 7) << 4)));
      o[dt] = __builtin_amdgcn_mfma_f32_16x16x32_bf16(pa, hf, o[dt], 0, 0, 0);
    }
  }

  // ---- combine wave pairs, epilogue ----
  __syncthreads();  // all tiles done; reuse smem[0,64K) = Kt+Ht as Ob
  float* Ob = (float*)smem;  // 4 pairs x [16][256] fp32 = 64 KB
  if (half == 1) {
#pragma unroll
    for (int dt = 0; dt < 16; ++dt)
#pragma unroll
      for (int r = 0; r < 4; ++r) {
        int row = hi * 4 + r;
        int byte = (row * 1024 + (dt * 16 + l15) * 4) ^ ((row & 15) << 6);
        *(float*)((char*)Ob + wg * 16384 + byte) = o[dt][r];
      }
    if (l15 == 0) {
#pragma unroll
      for (int r = 0; r < 4; ++r) {
        int row = wg * 16 + hi * 4 + r;
        Cm[row * 2] = mR[r];
        Cm[row * 2 + 1] = lR[r];
      }
    }
  }
  __syncthreads();
  if (half == 0) {
#pragma unroll
    for (int r = 0; r < 4; ++r) {
      int rowl = hi * 4 + r;
      float mB = Cm[(wg * 16 + rowl) * 2];
      float lB = Cm[(wg * 16 + rowl) * 2 + 1];
      float m = fmaxf(mR[r], mB);
      float cA = __expf(mR[r] - m), cB = __expf(mB - m);
      float inv = 1.f / (lR[r] * cA + lB * cB);
      int grow_ = b * 1024 + q0 + wg * 16 + rowl;
#pragma unroll
      for (int dt = 0; dt < 16; ++dt) {
        int byte = (rowl * 1024 + (dt * 16 + l15) * 4) ^ ((rowl & 15) << 6);
        float ob = *(const float*)((const char*)Ob + wg * 16384 + byte);
        float v = (o[dt][r] * cA + ob * cB) * inv;
        out[grow_ * 256 + dt * 16 + l15] = fmaxf(v, 0.f);
      }
    }
  }
}

// ---------------------------------------------------------------------------
extern "C" void kernel_launch(void* const* d_in, const int* in_sizes, int n_in,
                              void* d_out, int out_size, void* d_ws,
                              size_t ws_size, hipStream_t stream) {
  const float* feature = (const float*)d_in[0];
  const int* graph = (const int*)d_in[1];
  const float* W_w = (const float*)d_in[2];
  const float* W_b = (const float*)d_in[3];
  const float* Q_w = (const float*)d_in[4];
  const float* Q_b = (const float*)d_in[5];
  const float* K_w = (const float*)d_in[6];
  const float* K_b = (const float*)d_in[7];
  float* out = (float*)d_out;

  ushort* h = (ushort*)d_ws;          // [B,N,D] bf16   8 MB  (dead after q/k)
  ushort* hT = h + MTOT * DD;         // [B,D,N] bf16   8 MB
  ushort* q = hT + MTOT * DD;         // [B,N,D] bf16   8 MB
  ushort* k = q + MTOT * DD;          // [B,N,D] bf16   8 MB
  uint* maskG = (uint*)d_ws;          // [B,N,32] bits  2 MB — ALIASES h

  // h is consumed by the q/k GEMMs before pack_mask overwrites its buffer.
  gemm_hqk<true, true><<<256, 256, 0, stream>>>(feature, W_w, W_b, h, hT);
  gemm_hqk<false, false><<<256, 256, 0, stream>>>(h, Q_w, Q_b, q, nullptr);
  gemm_hqk<false, false><<<256, 256, 0, stream>>>(h, K_w, K_b, k, nullptr);
  pack_mask<<<2048, 256, 0, stream>>>(graph, maskG);
  attn8<<<256, 512, 0, stream>>>(q, k, hT, maskG, out);
}